// Round 2
// baseline (372.966 us; speedup 1.0000x reference)
//
#include <hip/hip_runtime.h>

// AdaptiveGraphConvolution on MI355X — round 4 (resubmit; round-1 bench was
// an infra failure "container failed twice", no counters returned).
// N=64, C=64, T=300, V=25, S=3 subsets, IC=16, O=64.
//
// Changes vs round 3:
//  * k1 xT staging swizzle: f(tv) = tv + (tv>>2) instead of f(tv)=tv.
//    Old pattern: per write instruction lanes share c with tv=4j+e ->
//    XOR block takes 2 values -> ~12-way bank conflict (matches the
//    measured 1.2e7 SQ_LDS_BANK_CONFLICT). New f walks 5j+e mod 8
//    through all 8 residues -> ~3-way worst case.
//  * k1 phase B: wave i owns subset i (waves 0..2 each do all 4 t
//    k-blocks). Each wave holds a complete M_i -> atomicAdd direct from
//    AGPRs. Removes the LDS Ms buffer zeroing, the 4-wave serialized
//    RMW reduction, and 6 barriers per block.
//  * k1 W staging: packed u32 writes (float2 reads), half the insts.
//  * k2 rewritten: 192 blocks (one per (i,n)) x 64 thr, Mb tile loaded
//    coalesced into LDS, softmax reads from LDS; gwb prep in 24 extra
//    blocks. (Old: 43 blocks, 75 stride-100B scattered loads/thread.)
// k3 unchanged.

#define NB 64
#define CB 64
#define TB 300
#define VB 25

typedef unsigned int uint32;
typedef unsigned short ushort16;
typedef __attribute__((ext_vector_type(8))) short short8;
typedef __attribute__((ext_vector_type(4))) float f32x4;
typedef __attribute__((ext_vector_type(16))) float f32x16;

__device__ __forceinline__ ushort16 f2bf(float f) {
    uint32 u = __float_as_uint(f);
    u = u + 0x7FFFu + ((u >> 16) & 1u);
    return (ushort16)(u >> 16);
}
__device__ __forceinline__ float bf2f(ushort16 h) {
    return __uint_as_float(((uint32)h) << 16);
}
__device__ __forceinline__ uint32 packbf2(float a, float b) {
    return (uint32)f2bf(a) | ((uint32)f2bf(b) << 16);
}

// xT swizzle: block position for c-block kb at row tv
__device__ __forceinline__ int xt_swz(int kb, int tv) {
    return ((kb + tv + (tv >> 2)) & 7) << 3;
}

// ---------------------------------------------------------------- kernel 1
// grid 1600 = 64 n * 25 chunks (12 t), 256 thr = 4 waves
__global__ __launch_bounds__(256) void k1_attn_logits_mfma(
    const float* __restrict__ x, const float* __restrict__ a_w,
    const float* __restrict__ a_b, const float* __restrict__ b_w,
    const float* __restrict__ b_b, float* __restrict__ Mb)
{
    __shared__ ushort16 ws[96 * 64];    // W bf16, row r, k-block swizzled (f(r)=r)
    __shared__ ushort16 xT[112 * 64];   // x^T bf16 [tv][c], swizzled f(tv)=tv+(tv>>2)
    __shared__ ushort16 abT[192 * 64];  // [g*32+v][k=(tl,ic)] bf16, swizzled f(v)=v
    __shared__ float    bias[96];

    const int tid   = threadIdx.x;
    const int n     = blockIdx.x / 25;
    const int chunk = blockIdx.x % 25;
    const float* xn = x + n * (CB * TB * VB);

    // W -> bf16 swizzled LDS (rows 0..47 = a_w, 48..95 = b_w), packed u32 writes
    for (int idx = tid; idx < 3072; idx += 256) {
        int r = idx >> 5, cp = idx & 31;
        int c = cp * 2;
        float2 v2 = (r < 48) ? *(const float2*)(a_w + r * 64 + c)
                             : *(const float2*)(b_w + (r - 48) * 64 + c);
        *(uint32*)&ws[r * 64 + ((((c >> 3) + r) & 7) << 3) + (c & 7)] =
            packbf2(v2.x, v2.y);
    }
    for (int idx = tid; idx < 96; idx += 256)
        bias[idx] = (idx < 48) ? a_b[idx] : b_b[idx - 48];

    const int w    = tid >> 6;
    const int lane = tid & 63;
    const int l15  = lane & 15;
    const int q    = lane >> 4;
    const int hi   = lane >> 5;
    const int v32  = lane & 31;

    f32x16 acc;                 // wave w (<3) accumulates M_{i=w}
    #pragma unroll
    for (int r = 0; r < 16; ++r) acc[r] = 0.f;
    const f32x4 zf = (f32x4){0.f, 0.f, 0.f, 0.f};

    for (int s = 0; s < 3; ++s) {
        __syncthreads();   // previous iter's xT/abT consumers done
        // ---- stage x^T sub-chunk (4 t = 100 contiguous floats per c-row)
        const float* xs0 = xn + (chunk * 12 + s * 4) * 25;
        for (int idx = tid; idx < 1600; idx += 256) {
            int c = idx / 25, j = idx % 25;
            float4 v4 = *(const float4*)(xs0 + c * 7500 + j * 4);
            int tv0 = j * 4;
            #pragma unroll
            for (int e = 0; e < 4; ++e) {
                int tv = tv0 + e;
                float fv = (e == 0) ? v4.x : (e == 1) ? v4.y : (e == 2) ? v4.z : v4.w;
                xT[tv * 64 + xt_swz(c >> 3, tv) + (c & 7)] = f2bf(fv);
            }
        }
        __syncthreads();
        // ---- phase A: ab = W @ x, write frags into abT operand layout
        for (int tile = w; tile < 42; tile += 4) {
            int rt = tile / 7, ct = tile % 7;
            int r  = rt * 16 + l15;
            int tv = ct * 16 + l15;
            f32x4 d = zf;
            #pragma unroll
            for (int ss = 0; ss < 2; ++ss) {
                int kb = ss * 4 + q;
                short8 af = *(const short8*)&ws[r * 64 + (((kb + r) & 7) << 3)];
                short8 bf = *(const short8*)&xT[tv * 64 + xt_swz(kb, tv)];
                d = __builtin_amdgcn_mfma_f32_16x16x32_bf16(af, bf, d, 0, 0, 0);
            }
            if (tv < 100) {
                int tl = tv / 25, v = tv % 25;
                int r0 = rt * 16 + q * 4;
                float b0 = bias[r0], b1 = bias[r0 + 1];
                float b2 = bias[r0 + 2], b3 = bias[r0 + 3];
                int kb = tl * 2 + (q >> 1);
                uint32* dst = (uint32*)&abT[(rt * 32 + v) * 64 +
                                            (((kb + v) & 7) << 3) + ((q & 1) << 2)];
                dst[0] = packbf2(d[0] + b0, d[1] + b1);
                dst[1] = packbf2(d[2] + b2, d[3] + b3);
            }
        }
        __syncthreads();
        // ---- phase B: wave w (<3) owns subset i=w, all 4 local t
        if (w < 3) {
            #pragma unroll
            for (int tl = 0; tl < 4; ++tl) {
                int kb = tl * 2 + hi;
                short8 af = *(const short8*)&abT[(w * 32 + v32) * 64 +
                                                 (((kb + v32) & 7) << 3)];
                short8 bf = *(const short8*)&abT[((3 + w) * 32 + v32) * 64 +
                                                 (((kb + v32) & 7) << 3)];
                acc = __builtin_amdgcn_mfma_f32_32x32x16_bf16(af, bf, acc, 0, 0, 0);
            }
        }
    }

    // ---- tail: each wave holds a full M_i -> atomics straight from regs
    if (w < 3 && v32 < 25) {
        const float inv = 1.0f / 4800.0f;
        #pragma unroll
        for (int r = 0; r < 16; ++r) {
            int row = (r & 3) + 8 * (r >> 2) + 4 * hi;   // m74/m101 C-layout
            if (row < 25)
                atomicAdd(Mb + ((w * NB + n) * 25 + row) * 25 + v32, acc[r] * inv);
        }
    }
}

// ---------------------------------------------------------------- kernel 2
// blocks 0..191: (i,n) softmax over v1 + A_tot -> atT bf16 [i][n][v2][v1 pad32]
// blocks 192..215: g_w -> gw_bf bf16 [o][k=i*64+c] (A-operand layout for k3)
__global__ __launch_bounds__(64) void k2_softmax_prep(
    const float* __restrict__ Mb, const float* __restrict__ A,
    const float* __restrict__ GA, const float* __restrict__ g_w,
    uint32* __restrict__ atT, uint32* __restrict__ gwb)
{
    const int b   = blockIdx.x;
    const int tid = threadIdx.x;
    if (b < 192) {
        __shared__ float Ms[640];
        const int i = b >> 6, n = b & 63;
        const float* src = Mb + b * 625;       // [i][n] tile, contiguous
        for (int idx = tid; idx < 625; idx += 64) Ms[idx] = src[idx];
        __syncthreads();
        if (tid < 25) {
            const int v2 = tid;
            float e[25], mx = -1e30f;
            #pragma unroll
            for (int v1 = 0; v1 < 25; ++v1) {
                e[v1] = Ms[v1 * 25 + v2];
                mx = fmaxf(mx, e[v1]);
            }
            float s = 0.f;
            #pragma unroll
            for (int v1 = 0; v1 < 25; ++v1) { e[v1] = __expf(e[v1] - mx); s += e[v1]; }
            float invs = 1.0f / s;
            const float* acol = A + i * 625 + v2;
            const float* gcol = GA + i * 625 + v2;
            float wv[25];
            #pragma unroll
            for (int v1 = 0; v1 < 25; ++v1)
                wv[v1] = e[v1] * invs + acol[v1 * 25] + gcol[v1 * 25];
            uint32* row = atT + ((i * 64 + n) * 32 + v2) * 16;
            #pragma unroll
            for (int p = 0; p < 12; ++p) row[p] = packbf2(wv[2 * p], wv[2 * p + 1]);
            row[12] = (uint32)f2bf(wv[24]);
            row[13] = 0u; row[14] = 0u; row[15] = 0u;
        }
    } else {
        int j0 = (b - 192) * 256 + tid * 4;
        #pragma unroll
        for (int u = 0; u < 4; ++u) {
            int j = j0 + u;                    // < 6144
            int o = j / 96, kp = j % 96;
            int k0 = 2 * kp, i = k0 >> 6, c = k0 & 63;
            float2 lh = *(const float2*)(g_w + (i * 64 + o) * 64 + c);
            gwb[j] = packbf2(lh.x, lh.y);
        }
    }
}

// ---------------------------------------------------------------- kernel 3
// MFMA. grid 3840 = 64 n * 60 chunks of 5 t; 256 thr = 4 waves (wave=o/c tile)
__global__ __launch_bounds__(256) void k3_out(
    const float* __restrict__ x, const uint32* __restrict__ atT,
    const ushort16* __restrict__ gwb, const float* __restrict__ g_b,
    const float* __restrict__ bn_g, const float* __restrict__ bn_b,
    const float* __restrict__ bn_m, const float* __restrict__ bn_v,
    float* __restrict__ out)
{
    __shared__ ushort16 xs[64 * 168];   // [c][t*32 + v1]  (stride 168: 2-way banks)
    __shared__ uint32  xa[128 * 36];    // [col=(t,v2) pad128][c: 72 bf16 as 36 u32]
    __shared__ uint32  ats[3 * 32 * 20];// [i][v2][v1: 40 bf16 as 20 u32]
    __shared__ float   bsc[64], bsh[64];

    const int tid = threadIdx.x;
    const int n  = blockIdx.x / 60;
    const int t0 = (blockIdx.x % 60) * 5;

    // stage x tile -> bf16 [c][t][v1]
    for (int idx = tid; idx < 8000; idx += 256) {
        int c = idx / 125, tv = idx % 125;
        int t = tv / 25, v = tv % 25;
        float g = x[((n * 64 + c) * 300 + t0 + t) * 25 + v];
        xs[c * 168 + t * 32 + v] = f2bf(g);
    }
    for (int idx = tid; idx < 64 * 35; idx += 256) {   // zero v1 in [25,32)
        int c = idx / 35, r = idx % 35;
        xs[c * 168 + (r / 7) * 32 + 25 + (r % 7)] = (ushort16)0;
    }
    // stage attn^T rows for this n
    for (int idx = tid; idx < 1536; idx += 256) {
        int row = idx >> 4, d = idx & 15;   // row = i*32+v2
        ats[row * 20 + d] = atT[((row >> 5) * 64 + n) * 512 + (row & 31) * 16 + d];
    }
    // BN scale/shift prefold (h = acc*sc + sh + x)
    for (int idx = tid; idx < 64; idx += 256) {
        float sc = bn_g[idx] * rsqrtf(bn_v[idx] + 1e-5f);
        bsc[idx] = sc;
        bsh[idx] = (g_b[idx] + g_b[64 + idx] + g_b[128 + idx] - bn_m[idx]) * sc + bn_b[idx];
    }
    // zero xa pad rows (cols 125..127)
    for (int idx = tid; idx < 3 * 36; idx += 256)
        xa[(125 + idx / 36) * 36 + idx % 36] = 0u;

    const int w    = tid >> 6;      // wave id = o-tile (main) = c-tile (xa)
    const int lane = tid & 63;
    const int l15  = lane & 15;
    const int q    = lane >> 4;

    // preload A-frags of gw (all 6 K-steps: k = i*64 + s*32)
    short8 gf[6];
    #pragma unroll
    for (int s = 0; s < 6; ++s)
        gf[s] = *(const short8*)(gwb + ((w * 16 + l15) * 192 + s * 32 + q * 8));

    f32x4 acc[8];
    #pragma unroll
    for (int ct = 0; ct < 8; ++ct) acc[ct] = (f32x4){0.f, 0.f, 0.f, 0.f};
    const f32x4 zf = (f32x4){0.f, 0.f, 0.f, 0.f};

    __syncthreads();

    for (int i = 0; i < 3; ++i) {
        if (i) __syncthreads();   // previous xa fully consumed
        // ---- xa-phase: this wave produces c-rows [w*16, w*16+16)
        #pragma unroll
        for (int t = 0; t < 5; ++t) {
            short8 ax = *(const short8*)(xs + (w * 16 + l15) * 168 + t * 32 + q * 8);
            #pragma unroll
            for (int vt = 0; vt < 2; ++vt) {
                short8 bt = *(const short8*)((const ushort16*)ats +
                                             (i * 32 + vt * 16 + l15) * 40 + q * 8);
                f32x4 d = __builtin_amdgcn_mfma_f32_16x16x32_bf16(ax, bt, zf, 0, 0, 0);
                int v2 = vt * 16 + l15;
                if (v2 < 25) {
                    int col = t * 25 + v2;
                    int c0  = w * 16 + q * 4;
                    xa[col * 36 + (c0 >> 1)]     = packbf2(d[0], d[1]);
                    xa[col * 36 + (c0 >> 1) + 1] = packbf2(d[2], d[3]);
                }
            }
        }
        __syncthreads();
        // ---- main GEMM: acc[o,col] += gw_i[o,c] * xa[c,col]
        #pragma unroll
        for (int ct = 0; ct < 8; ++ct) {
            #pragma unroll
            for (int s = 0; s < 2; ++s) {
                short8 bfrag = *(const short8*)((const ushort16*)xa +
                                                (ct * 16 + l15) * 72 + s * 32 + q * 8);
                acc[ct] = __builtin_amdgcn_mfma_f32_16x16x32_bf16(
                    gf[i * 2 + s], bfrag, acc[ct], 0, 0, 0);
            }
        }
    }

    // ---- epilogue: BN + residual (bf16 xs) + relu, direct coalesced store
    const int o0 = w * 16 + q * 4;
    #pragma unroll
    for (int ct = 0; ct < 8; ++ct) {
        int col = ct * 16 + l15;
        if (col < 125) {
            int tl = col / 25;
            int v  = col - tl * 25;
            float* ob = out + (n * 64 + o0) * 7500 + t0 * 25 + col;
            #pragma unroll
            for (int r = 0; r < 4; ++r) {
                int o = o0 + r;
                float xv = bf2f(xs[o * 168 + tl * 32 + v]);
                float h = acc[ct][r] * bsc[o] + bsh[o] + xv;
                ob[r * 7500] = fmaxf(h, 0.f);
            }
        }
    }
}

// ---------------------------------------------------------------- launch
extern "C" void kernel_launch(void* const* d_in, const int* in_sizes, int n_in,
                              void* d_out, int out_size, void* d_ws, size_t ws_size,
                              hipStream_t stream) {
    const float* x    = (const float*)d_in[0];
    const float* A    = (const float*)d_in[1];
    const float* GA   = (const float*)d_in[2];
    const float* g_w  = (const float*)d_in[3];
    const float* g_b  = (const float*)d_in[4];
    const float* a_w  = (const float*)d_in[5];
    const float* a_b  = (const float*)d_in[6];
    const float* b_w  = (const float*)d_in[7];
    const float* b_b  = (const float*)d_in[8];
    const float* bn_g = (const float*)d_in[9];
    const float* bn_b = (const float*)d_in[10];
    const float* bn_m = (const float*)d_in[11];
    const float* bn_v = (const float*)d_in[12];
    float* out = (float*)d_out;

    // ws: Mb f32[120000] (480000 B) | atT bf16 [3][64][32][32] (393216 B)
    //     | gw_bf bf16 [64][192] (24576 B)
    float*  Mb  = (float*)d_ws;
    uint32* atT = (uint32*)((char*)d_ws + 480000);
    uint32* gwb = (uint32*)((char*)d_ws + 480000 + 393216);

    hipMemsetAsync(d_ws, 0, 480000, stream);  // zero M accumulators
    k1_attn_logits_mfma<<<dim3(1600), dim3(256), 0, stream>>>(x, a_w, a_b, b_w, b_b, Mb);
    k2_softmax_prep<<<dim3(216), dim3(64), 0, stream>>>(Mb, A, GA, g_w, atT, gwb);
    k3_out<<<dim3(3840), dim3(256), 0, stream>>>(x, atT, (const ushort16*)gwb,
                                                 g_b, bn_g, bn_b, bn_m, bn_v, out);
}